// Round 1
// baseline (201.972 us; speedup 1.0000x reference)
//
#include <hip/hip_runtime.h>
#include <math.h>

// SSIM, fully fused single pass.
// Layout: img1/img2 are [16][3][512][512] fp32. Output: 1 fp32 scalar (mean SSIM).
// Separable 11-tap Gaussian (sigma=1.5), zero padding (pad=5), matching
// jax.lax.conv_general_dilated with padding [(5,5),(5,5)].
//
// Block = 256 threads, tile = 256 cols x 64 rows of one (n,c) plane.
// Per image row: stage 266-px row slice of both images in LDS (double-buffered,
// one __syncthreads per row), horizontal 11-tap conv per thread-column for the
// 5 quantities (x, y, x^2, y^2, xy), push into an 11-deep register sliding
// window, vertical 11-tap dot from registers + SSIM formula + accumulate.

#define TX 256
#define TY 64
#define RAD 5
#define KW 11
#define LW (TX + 2 * RAD)   // 266
#define IMG_W 512
#define IMG_H 512
#define C1F 0.0001f          // 0.01^2
#define C2F 0.0009f          // 0.03^2

__global__ __launch_bounds__(256) void ssim_fused_kernel(
    const float* __restrict__ img1,
    const float* __restrict__ img2,
    float* __restrict__ out,
    float inv_n)
{
    __shared__ float r1[2][LW];
    __shared__ float r2[2][LW];
    __shared__ float red[4];

    const int tid = threadIdx.x;
    const int x0  = blockIdx.x * TX;
    const int y0  = blockIdx.y * TY;
    const size_t pbase = (size_t)blockIdx.z * (size_t)(IMG_W * IMG_H);
    const float* __restrict__ p1 = img1 + pbase;
    const float* __restrict__ p2 = img2 + pbase;

    // Gaussian weights in double (matches float64 np reference to fp32 ulp).
    // Uniform across threads -> pin to SGPRs via readfirstlane.
    float g[KW];
    {
        double t[KW];
        double s = 0.0;
        #pragma unroll
        for (int i = 0; i < KW; ++i) {
            const double c = (double)(i - RAD);
            t[i] = exp(-(c * c) / 4.5);   // 2*sigma^2 = 4.5
            s += t[i];
        }
        #pragma unroll
        for (int i = 0; i < KW; ++i) {
            const float gi = (float)(t[i] / s);
            g[i] = __int_as_float(__builtin_amdgcn_readfirstlane(__float_as_int(gi)));
        }
    }

    // 11-deep sliding windows of horizontal conv results (registers).
    float wx[KW], wy[KW], wxx[KW], wyy[KW], wxy[KW];
    #pragma unroll
    for (int k = 0; k < KW; ++k) {
        wx[k] = 0.f; wy[k] = 0.f; wxx[k] = 0.f; wyy[k] = 0.f; wxy[k] = 0.f;
    }

    float acc = 0.f;

    const int nrows = TY + 2 * RAD;   // 74
    #pragma clang loop unroll(disable)
    for (int j = 0; j < nrows; ++j) {
        const int ir  = y0 - RAD + j;
        const int buf = j & 1;
        const bool rowok = ((unsigned)ir < (unsigned)IMG_H);
        const size_t rowbase = (size_t)ir * IMG_W;

        // Stage row ir (cols x0-5 .. x0+260) of both images into LDS.
        for (int t = tid; t < LW; t += TX) {
            const int gx = x0 + t - RAD;
            float a = 0.f, b = 0.f;
            if (rowok && ((unsigned)gx < (unsigned)IMG_W)) {
                a = p1[rowbase + gx];
                b = p2[rowbase + gx];
            }
            r1[buf][t] = a;
            r2[buf][t] = b;
        }
        __syncthreads();
        // (double buffer: slot reused at j+2; the sync at j+1 orders it)

        // Horizontal 11-tap conv at column tid for 5 quantities.
        float hx = 0.f, hy = 0.f, hxx = 0.f, hyy = 0.f, hxy = 0.f;
        #pragma unroll
        for (int k = 0; k < KW; ++k) {
            const float a  = r1[buf][tid + k];
            const float b  = r2[buf][tid + k];
            const float wk = g[k];
            const float wa = wk * a;
            const float wb = wk * b;
            hx += wa;
            hy += wb;
            hxx = fmaf(wa, a, hxx);
            hyy = fmaf(wb, b, hyy);
            hxy = fmaf(wa, b, hxy);
        }

        // Shift windows, push new row.
        #pragma unroll
        for (int k = 0; k < KW - 1; ++k) {
            wx[k]  = wx[k + 1];
            wy[k]  = wy[k + 1];
            wxx[k] = wxx[k + 1];
            wyy[k] = wyy[k + 1];
            wxy[k] = wxy[k + 1];
        }
        wx[KW - 1]  = hx;
        wy[KW - 1]  = hy;
        wxx[KW - 1] = hxx;
        wyy[KW - 1] = hyy;
        wxy[KW - 1] = hxy;

        // Once 11 rows are in the window, emit output row ir-5.
        if (j >= KW - 1) {   // uniform branch
            float mu1 = 0.f, mu2 = 0.f, ex2 = 0.f, ey2 = 0.f, exy = 0.f;
            #pragma unroll
            for (int k = 0; k < KW; ++k) {
                const float wk = g[k];
                mu1 = fmaf(wk, wx[k],  mu1);
                mu2 = fmaf(wk, wy[k],  mu2);
                ex2 = fmaf(wk, wxx[k], ex2);
                ey2 = fmaf(wk, wyy[k], ey2);
                exy = fmaf(wk, wxy[k], exy);
            }
            const float mu11 = mu1 * mu1;
            const float mu22 = mu2 * mu2;
            const float mu12 = mu1 * mu2;
            const float s1   = ex2 - mu11;   // sigma1_sq
            const float s2   = ey2 - mu22;   // sigma2_sq
            const float s12  = exy - mu12;   // sigma12
            const float num  = (2.f * mu12 + C1F) * (2.f * s12 + C2F);
            const float den  = (mu11 + mu22 + C1F) * (s1 + s2 + C2F);
            acc += num / den;
        }
    }

    // Wave butterfly reduce, then block reduce, one atomic per block.
    #pragma unroll
    for (int off = 32; off > 0; off >>= 1)
        acc += __shfl_xor(acc, off, 64);
    if ((tid & 63) == 0) red[tid >> 6] = acc;
    __syncthreads();
    if (tid == 0) {
        const float s = red[0] + red[1] + red[2] + red[3];
        atomicAdd(out, s * inv_n);
    }
}

extern "C" void kernel_launch(void* const* d_in, const int* in_sizes, int n_in,
                              void* d_out, int out_size, void* d_ws, size_t ws_size,
                              hipStream_t stream) {
    const float* img1 = (const float*)d_in[0];
    const float* img2 = (const float*)d_in[1];
    float* out = (float*)d_out;

    // d_out is re-poisoned to 0xAA before every launch; zero it (capture-safe).
    hipMemsetAsync(out, 0, (size_t)out_size * sizeof(float), stream);

    const float inv_n = 1.0f / (16.0f * 3.0f * 512.0f * 512.0f);
    dim3 grid(IMG_W / TX, IMG_H / TY, 16 * 3);   // (2, 8, 48) = 768 blocks
    ssim_fused_kernel<<<grid, dim3(256, 1, 1), 0, stream>>>(img1, img2, out, inv_n);
}

// Round 2
// 171.083 us; speedup vs baseline: 1.1806x; 1.1806x over previous
//
#include <hip/hip_runtime.h>
#include <math.h>

// SSIM fused single pass, v2.
// - 11-phase unrolled row loop: vertical conv via mod-11 scatter accumulators
//   (compile-time slot indices) -> no window-shift movs, 55 FMA/row total.
// - Packed fp32: (img1,img2) quantities paired as float2 ext-vectors so the
//   backend can emit v_pk_fma_f32 / v_pk_mul_f32 (full-rate packed on CDNA).
// - LDS stores (a,b) interleaved pairs -> one ds_read_b64 per tap (11/row).
// - TY=34 (44 row-iters = 4*11) -> 1536 blocks for occupancy.

#define TX 256
#define TY 34
#define RAD 5
#define KW 11
#define LWP (TX + 2 * RAD)   // 266 (a,b) pairs per row buffer
#define IMG_W 512
#define IMG_H 512
#define C1F 0.0001f          // 0.01^2
#define C2F 0.0009f          // 0.03^2

typedef float v2f __attribute__((ext_vector_type(2)));

__global__ __launch_bounds__(256, 5) void ssim_fused_kernel(
    const float* __restrict__ img1,
    const float* __restrict__ img2,
    float* __restrict__ out,
    float inv_n)
{
    __shared__ v2f rows[2][LWP];   // (a,b) pairs, double-buffered
    __shared__ float red[4];

    const int tid = threadIdx.x;
    const int x0  = blockIdx.x * TX;
    const int y0  = blockIdx.y * TY;
    const float* __restrict__ p1 = img1 + blockIdx.z * (IMG_W * IMG_H);
    const float* __restrict__ p2 = img2 + blockIdx.z * (IMG_W * IMG_H);

    // Gaussian weights in double (matches float64 reference to fp32 ulp),
    // pinned to SGPRs.
    float g[KW];
    {
        double t[KW];
        double s = 0.0;
        #pragma unroll
        for (int i = 0; i < KW; ++i) {
            const double c = (double)(i - RAD);
            t[i] = exp(-(c * c) / 4.5);   // 2*sigma^2 = 4.5
            s += t[i];
        }
        #pragma unroll
        for (int i = 0; i < KW; ++i) {
            const float gi = (float)(t[i] / s);
            g[i] = __int_as_float(__builtin_amdgcn_readfirstlane(__float_as_int(gi)));
        }
    }

    // Vertical scatter accumulators: slot s holds output row m with m%11==s.
    v2f  accMu[KW];   // (mu1, mu2) weighted sums
    v2f  accSq[KW];   // (E[x^2], E[y^2]) weighted sums
    float accXy[KW];  // E[x*y] weighted sum
    #pragma unroll
    for (int s = 0; s < KW; ++s) {
        accMu[s] = (v2f){0.f, 0.f};
        accSq[s] = (v2f){0.f, 0.f};
        accXy[s] = 0.f;
    }

    float acc = 0.f;

    const int gx0 = x0 - RAD + tid;   // col staged at pair index tid
    const int gx1 = gx0 + TX;         // col staged at pair index TX+tid (tid<10)

    #pragma clang loop unroll(disable)
    for (int jb = 0; jb < 4; ++jb) {
        #pragma unroll
        for (int P = 0; P < KW; ++P) {
            const int j  = jb * KW + P;          // h-row local index, 0..43
            const int ir = y0 - RAD + j;         // image row
            const int buf = j & 1;
            const bool rowok = ((unsigned)ir < (unsigned)IMG_H);
            const int rb = ir * IMG_W;

            // ---- stage row ir as (a,b) pairs ----
            {
                v2f ab = (v2f){0.f, 0.f};
                if (rowok && ((unsigned)gx0 < (unsigned)IMG_W)) {
                    ab.x = p1[rb + gx0];
                    ab.y = p2[rb + gx0];
                }
                rows[buf][tid] = ab;
                if (tid < 2 * RAD) {
                    v2f ab2 = (v2f){0.f, 0.f};
                    if (rowok && ((unsigned)gx1 < (unsigned)IMG_W)) {
                        ab2.x = p1[rb + gx1];
                        ab2.y = p2[rb + gx1];
                    }
                    rows[buf][TX + tid] = ab2;
                }
            }
            __syncthreads();
            // (double buffer: slot reused at j+2, ordered by the j+1 barrier)

            // ---- horizontal 11-tap conv (packed) ----
            v2f hmu = (v2f){0.f, 0.f};   // (hx, hy)
            v2f hsq = (v2f){0.f, 0.f};   // (hxx, hyy)
            float hxy = 0.f;
            #pragma unroll
            for (int k = 0; k < KW; ++k) {
                const v2f ab = rows[buf][tid + k];   // ds_read_b64
                const v2f w  = g[k] * ab;            // v_pk_mul
                hmu += w;                            // v_pk_add
                hsq = __builtin_elementwise_fma(w, ab, hsq);   // v_pk_fma
                hxy = fmaf(w.x, ab.y, hxy);          // scalar fma
            }

            // ---- vertical scatter: slot s gets weight g[(P-s) mod 11] ----
            #pragma unroll
            for (int s = 0; s < KW; ++s) {
                const float wt = g[(P - s + KW) % KW];
                const v2f wv = (v2f){wt, wt};
                accMu[s] = __builtin_elementwise_fma(wv, hmu, accMu[s]);
                accSq[s] = __builtin_elementwise_fma(wv, hsq, accSq[s]);
                accXy[s] = fmaf(wt, hxy, accXy[s]);
            }

            // ---- emit completed output row m=j-10 from slot (P+1)%11 ----
            const int e  = (P + 1) % KW;
            const int oi = y0 + j - 2 * RAD;
            if (j >= 2 * RAD && oi < IMG_H) {   // uniform branch
                const v2f mu   = accMu[e];
                const v2f musq = mu * mu;
                const float mu12 = mu.x * mu.y;
                const v2f sig  = accSq[e] - musq;      // (sigma1_sq, sigma2_sq)
                const float s12 = accXy[e] - mu12;     // sigma12
                const float num = (2.f * mu12 + C1F) * (2.f * s12 + C2F);
                const float den = (musq.x + musq.y + C1F) * (sig.x + sig.y + C2F);
                acc += num / den;
            }
            // reset slot for its next output (m+11); harmless in prologue/tail
            accMu[e] = (v2f){0.f, 0.f};
            accSq[e] = (v2f){0.f, 0.f};
            accXy[e] = 0.f;
        }
    }

    // ---- block reduction, one atomic per block ----
    #pragma unroll
    for (int off = 32; off > 0; off >>= 1)
        acc += __shfl_xor(acc, off, 64);
    if ((tid & 63) == 0) red[tid >> 6] = acc;
    __syncthreads();
    if (tid == 0) {
        const float s = red[0] + red[1] + red[2] + red[3];
        atomicAdd(out, s * inv_n);
    }
}

extern "C" void kernel_launch(void* const* d_in, const int* in_sizes, int n_in,
                              void* d_out, int out_size, void* d_ws, size_t ws_size,
                              hipStream_t stream) {
    const float* img1 = (const float*)d_in[0];
    const float* img2 = (const float*)d_in[1];
    float* out = (float*)d_out;

    // d_out is re-poisoned to 0xAA before every launch; zero it (capture-safe).
    hipMemsetAsync(out, 0, (size_t)out_size * sizeof(float), stream);

    const float inv_n = 1.0f / (16.0f * 3.0f * 512.0f * 512.0f);
    // grid.y covers 16*34=544 rows; tail rows masked in-kernel.
    dim3 grid(IMG_W / TX, (IMG_H + TY - 1) / TY, 16 * 3);   // (2,16,48)=1536 blocks
    ssim_fused_kernel<<<grid, dim3(256, 1, 1), 0, stream>>>(img1, img2, out, inv_n);
}